// Round 1
// baseline (396.507 us; speedup 1.0000x reference)
//
#include <hip/hip_runtime.h>
#include <math.h>

// Problem constants (B,L,H,D) = (2,4096,8,64); sample_k = n_top = 45
#define B_ 2
#define L_ 4096
#define H_ 8
#define D_ 64
#define S_ 45
#define NTOP_ 45
#define SCALE 0.125f  // 1/sqrt(64)

// ---------------- K0: zero the output ----------------
__global__ __launch_bounds__(256) void zero_out_kernel(float4* __restrict__ out, int n4) {
    int i = blockIdx.x * 256 + threadIdx.x;
    if (i < n4) out[i] = make_float4(0.f, 0.f, 0.f, 0.f);
}

// ---------------- K1: sparsity measure M = max_s(q.k_s) - mean_s over L_K ----------------
// One wave handles 4 queries; 16 lanes per query, each lane holds a float4 of D.
__global__ __launch_bounds__(256) void compute_M_kernel(
    const float* __restrict__ q, const float* __restrict__ k,
    const int* __restrict__ samp, float* __restrict__ M) {
    int tid  = threadIdx.x;
    int wave = tid >> 6;          // 0..3
    int lane = tid & 63;
    int sub  = lane >> 4;         // 0..3 : which query within the wave
    int l16  = lane & 15;         // 0..15: float4 slot within D=64

    long gq = ((long)blockIdx.x * 4 + wave) * 4 + sub;   // 0..65535 = (bh, l)
    int bh = (int)(gq >> 12);
    int l  = (int)(gq & (L_ - 1));
    int b = bh >> 3, h = bh & 7;

    const float4* qv = (const float4*)(q + (((long)(b * L_ + l)) * H_ + h) * D_);
    float4 qf = qv[l16];

    const int* srow = samp + (long)l * S_;
    float vmax = -INFINITY, vsum = 0.f;
    for (int s = 0; s < S_; ++s) {
        int idx = srow[s];
        const float4* kv = (const float4*)(k + (((long)(b * L_ + idx)) * H_ + h) * D_);
        float4 kf = kv[l16];
        float p = qf.x * kf.x + qf.y * kf.y + qf.z * kf.z + qf.w * kf.w;
        p += __shfl_xor(p, 1, 64);
        p += __shfl_xor(p, 2, 64);
        p += __shfl_xor(p, 4, 64);
        p += __shfl_xor(p, 8, 64);
        vmax = fmaxf(vmax, p);
        vsum += p;
    }
    if (l16 == 0) M[(long)bh * L_ + l] = vmax - vsum * (1.0f / (float)L_);
}

// ---------------- K2: top-45 of M per (b,h), lowest-index tie-break ----------------
__global__ __launch_bounds__(256) void topk_kernel(
    const float* __restrict__ M, int* __restrict__ topIdx) {
    __shared__ float sm[L_];
    __shared__ float rv[256];
    __shared__ int   ri[256];
    int bh  = blockIdx.x;
    int tid = threadIdx.x;
    const float* row = M + (long)bh * L_;
    for (int i = tid; i < L_; i += 256) sm[i] = row[i];
    __syncthreads();
    for (int t = 0; t < NTOP_; ++t) {
        float bv = -INFINITY; int bi = 0x7fffffff;
        int base = tid * 16;  // blocked: local lowest-index tie-break == global
        #pragma unroll
        for (int j = 0; j < 16; ++j) {
            float vv = sm[base + j];
            if (vv > bv) { bv = vv; bi = base + j; }
        }
        rv[tid] = bv; ri[tid] = bi;
        __syncthreads();
        for (int off = 128; off > 0; off >>= 1) {
            if (tid < off) {
                float ov = rv[tid + off]; int oi = ri[tid + off];
                if (ov > rv[tid] || (ov == rv[tid] && oi < ri[tid])) {
                    rv[tid] = ov; ri[tid] = oi;
                }
            }
            __syncthreads();
        }
        if (tid == 0) {
            topIdx[bh * NTOP_ + t] = ri[0];
            sm[ri[0]] = -INFINITY;
        }
        __syncthreads();
    }
}

// ---------------- K3: full attention for the selected queries, scatter to out ----------------
// grid = (NTOP_, B*H); one block per selected query.
__global__ __launch_bounds__(256) void attn_top_kernel(
    const float* __restrict__ q, const float* __restrict__ k,
    const float* __restrict__ v, const int* __restrict__ topIdx,
    float* __restrict__ out) {
    __shared__ float sq[D_];
    __shared__ float sc[L_];
    __shared__ float red[256];
    __shared__ float part[4 * D_];

    int u  = blockIdx.x;      // 0..44
    int bh = blockIdx.y;      // 0..15
    int b = bh >> 3, h = bh & 7;
    int tid = threadIdx.x;
    int lq = topIdx[bh * NTOP_ + u];

    if (tid < D_) sq[tid] = q[(((long)(b * L_ + lq)) * H_ + h) * D_ + tid];
    __syncthreads();

    // scores: thread t handles keys t, t+256, ... (16 keys)
    const float4* q4 = (const float4*)sq;
    float lmax = -INFINITY;
    #pragma unroll 1
    for (int j = 0; j < 16; ++j) {
        int key = tid + 256 * j;
        const float4* kv = (const float4*)(k + (((long)(b * L_ + key)) * H_ + h) * D_);
        float acc = 0.f;
        #pragma unroll
        for (int d4 = 0; d4 < 16; ++d4) {
            float4 kf = kv[d4]; float4 qf = q4[d4];
            acc += qf.x * kf.x + qf.y * kf.y + qf.z * kf.z + qf.w * kf.w;
        }
        acc *= SCALE;
        sc[key] = acc;
        lmax = fmaxf(lmax, acc);
    }
    red[tid] = lmax;
    __syncthreads();
    for (int off = 128; off > 0; off >>= 1) {
        if (tid < off) red[tid] = fmaxf(red[tid], red[tid + off]);
        __syncthreads();
    }
    float m = red[0];
    __syncthreads();

    float lsum = 0.f;
    #pragma unroll 1
    for (int j = 0; j < 16; ++j) {
        int key = tid + 256 * j;
        float e = __expf(sc[key] - m);
        sc[key] = e;
        lsum += e;
    }
    red[tid] = lsum;
    __syncthreads();
    for (int off = 128; off > 0; off >>= 1) {
        if (tid < off) red[tid] += red[tid + off];
        __syncthreads();
    }
    float inv = 1.0f / red[0];
    __syncthreads();

    // PV: 4 chunks of 1024 keys x 64 dims; wave c handles chunk c -> coalesced v reads
    int d = tid & 63;
    int chunk = tid >> 6;
    float acc = 0.f;
    for (int j = 0; j < 1024; ++j) {
        int key = chunk * 1024 + j;
        acc += sc[key] * v[(((long)(b * L_ + key)) * H_ + h) * D_ + d];
    }
    part[chunk * D_ + d] = acc;
    __syncthreads();
    if (tid < D_) {
        float o = (part[tid] + part[D_ + tid] + part[2 * D_ + tid] + part[3 * D_ + tid]) * inv;
        out[(((long)(b * L_ + lq)) * H_ + h) * D_ + tid] = o;
    }
}

extern "C" void kernel_launch(void* const* d_in, const int* in_sizes, int n_in,
                              void* d_out, int out_size, void* d_ws, size_t ws_size,
                              hipStream_t stream) {
    const float* q = (const float*)d_in[0];
    const float* k = (const float*)d_in[1];
    const float* v = (const float*)d_in[2];
    // d_in[3] = attn_mask (unused by reference)
    const int* samp = (const int*)d_in[4];
    float* out = (float*)d_out;

    float* M = (float*)d_ws;                                      // B*H*L floats = 256 KB
    int* topIdx = (int*)((char*)d_ws + (size_t)B_ * H_ * L_ * sizeof(float)); // 16*45 ints

    int n4 = out_size / 4;
    zero_out_kernel<<<(n4 + 255) / 256, 256, 0, stream>>>((float4*)d_out, n4);

    // 65536 queries / (4 per wave) / (4 waves per block) = 4096 blocks
    compute_M_kernel<<<4096, 256, 0, stream>>>(q, k, samp, M);

    topk_kernel<<<B_ * H_, 256, 0, stream>>>(M, topIdx);

    dim3 g3(NTOP_, B_ * H_);
    attn_top_kernel<<<g3, 256, 0, stream>>>(q, k, v, topIdx, out);
}

// Round 2
// 239.390 us; speedup vs baseline: 1.6563x; 1.6563x over previous
//
#include <hip/hip_runtime.h>
#include <math.h>

// Problem constants (B,L,H,D) = (2,4096,8,64); sample_k = n_top = 45
#define B_ 2
#define L_ 4096
#define H_ 8
#define D_ 64
#define S_ 45
#define NTOP_ 45
#define SCALE 0.125f  // 1/sqrt(64)
#define SPLITS 32
#define TKEYS 128     // keys per strip block

// ---------------- K1: sparsity measure M = max_s(q.k_s) - sum_s/L ----------------
// One wave handles 4 queries; 16 lanes per query, each lane a float4 of D.
// XCD swizzle: blockIdx%8 selects bh%8 so each XCD's K-gathers stay in a 2MB slice.
__global__ __launch_bounds__(256) void compute_M_kernel(
    const float* __restrict__ q, const float* __restrict__ k,
    const int* __restrict__ samp, float* __restrict__ M) {
    int tid  = threadIdx.x;
    int wave = tid >> 6;
    int lane = tid & 63;
    int sub  = lane >> 4;
    int l16  = lane & 15;

    int g    = blockIdx.x;          // 0..4095
    int xcd  = g & 7;
    int s0   = g >> 3;              // 0..511
    int bh   = xcd + 8 * (s0 >> 8); // 2 bh per XCD
    int chunk = s0 & 255;
    int l    = chunk * 16 + wave * 4 + sub;
    int b = bh >> 3, h = bh & 7;

    const float4* qv = (const float4*)(q + (((long)(b * L_ + l)) * H_ + h) * D_);
    float4 qf = qv[l16];

    const int* srow = samp + (long)l * S_;
    float vmax = -INFINITY, vsum = 0.f;
    #pragma unroll 5
    for (int s = 0; s < S_; ++s) {
        int idx = srow[s];
        const float4* kv = (const float4*)(k + (((long)(b * L_ + idx)) * H_ + h) * D_);
        float4 kf = kv[l16];
        float p = qf.x * kf.x + qf.y * kf.y + qf.z * kf.z + qf.w * kf.w;
        p += __shfl_xor(p, 1, 64);
        p += __shfl_xor(p, 2, 64);
        p += __shfl_xor(p, 4, 64);
        p += __shfl_xor(p, 8, 64);
        vmax = fmaxf(vmax, p);
        vsum += p;
    }
    if (l16 == 0) M[(long)bh * L_ + l] = vmax - vsum * (1.0f / (float)L_);
}

// ---------------- K2: top-45 of M per (b,h), lowest-index tie-break ----------------
__global__ __launch_bounds__(256) void topk_kernel(
    const float* __restrict__ M, int* __restrict__ topIdx) {
    __shared__ float sm[L_];
    __shared__ float rv[4];
    __shared__ int   ri[4];
    int bh  = blockIdx.x;
    int tid = threadIdx.x;
    const float* row = M + (long)bh * L_;
    for (int i = tid; i < L_; i += 256) sm[i] = row[i];
    __syncthreads();
    for (int t = 0; t < NTOP_; ++t) {
        float bv = -INFINITY; int bi = 0x7fffffff;
        // interleaved scan: conflict-free; within-thread indices ascend -> lowest-index tie-break
        #pragma unroll
        for (int j = 0; j < 16; ++j) {
            int idx = tid + 256 * j;
            float vv = sm[idx];
            if (vv > bv) { bv = vv; bi = idx; }
        }
        // wave shuffle reduce (value, index) with tie-break
        #pragma unroll
        for (int off = 1; off < 64; off <<= 1) {
            float ov = __shfl_xor(bv, off, 64);
            int   oi = __shfl_xor(bi, off, 64);
            if (ov > bv || (ov == bv && oi < bi)) { bv = ov; bi = oi; }
        }
        int w = tid >> 6;
        if ((tid & 63) == 0) { rv[w] = bv; ri[w] = bi; }
        __syncthreads();
        if (tid == 0) {
            float fv = rv[0]; int fi = ri[0];
            #pragma unroll
            for (int w2 = 1; w2 < 4; ++w2) {
                if (rv[w2] > fv || (rv[w2] == fv && ri[w2] < fi)) { fv = rv[w2]; fi = ri[w2]; }
            }
            topIdx[bh * NTOP_ + t] = fi;
            sm[fi] = -INFINITY;
        }
        __syncthreads();
    }
}

// ---------------- K3: key-strip attention, all 45 queries per (b,h) share K/V tile ----------------
// 1D grid of 512 blocks, XCD-swizzled: xcd = g&7 -> bh in {xcd, xcd+8}, split = s&31.
#define QSTRIDE 68    // padded LDS row stride for Q and K/V tiles (floats)
#define PSTRIDE 132   // padded LDS row stride for P (floats)
__global__ __launch_bounds__(256, 2) void attn_strip_kernel(
    const float* __restrict__ q, const float* __restrict__ k,
    const float* __restrict__ v, const int* __restrict__ topIdx,
    float* __restrict__ out, float* __restrict__ pl) {
    __shared__ int   sTop[48];
    __shared__ float sQ[48 * QSTRIDE];    // 13.1 KB
    __shared__ float sKV[TKEYS * QSTRIDE]; // 34.8 KB (K, then reused for V)
    __shared__ float sP[48 * PSTRIDE];    // 25.3 KB

    int g = blockIdx.x;
    int xcd = g & 7;
    int s0 = g >> 3;                // 0..63
    int bh = xcd + 8 * (s0 >> 5);
    int split = s0 & 31;
    int b = bh >> 3, h = bh & 7;
    int tid = threadIdx.x;
    int key0 = split * TKEYS;

    if (tid < NTOP_) sTop[tid] = topIdx[bh * NTOP_ + tid];
    __syncthreads();

    // load Q: 45 rows x 16 float4 (pad rows 45..47 with zeros)
    for (int i = tid; i < 768; i += 256) {
        int u = i >> 4, d4 = i & 15;
        float4 val = make_float4(0.f, 0.f, 0.f, 0.f);
        if (u < NTOP_) {
            int lq = sTop[u];
            val = *(const float4*)(q + (((long)(b * L_ + lq)) * H_ + h) * D_ + 4 * d4);
        }
        *(float4*)(sQ + u * QSTRIDE + 4 * d4) = val;
    }
    // load K tile: 128 rows x 16 float4
    #pragma unroll
    for (int j = 0; j < 8; ++j) {
        int i = tid + 256 * j;
        int r = i >> 4, d4 = i & 15;
        float4 val = *(const float4*)(k + (((long)(b * L_ + key0 + r)) * H_ + h) * D_ + 4 * d4);
        *(float4*)(sKV + r * QSTRIDE + 4 * d4) = val;
    }
    __syncthreads();

    // S phase: thread (ty,tx) computes u = 3ty+i (i<3) x keys tx+16j (j<8)
    int tx = tid & 15, ty = tid >> 4;
    float acc[3][8];
    #pragma unroll
    for (int i = 0; i < 3; ++i)
        #pragma unroll
        for (int j = 0; j < 8; ++j) acc[i][j] = 0.f;

    #pragma unroll 4
    for (int d4 = 0; d4 < 16; ++d4) {
        float4 qv[3];
        #pragma unroll
        for (int i = 0; i < 3; ++i)
            qv[i] = *(const float4*)(sQ + (3 * ty + i) * QSTRIDE + 4 * d4);
        #pragma unroll
        for (int j = 0; j < 8; ++j) {
            float4 kv = *(const float4*)(sKV + (tx + 16 * j) * QSTRIDE + 4 * d4);
            #pragma unroll
            for (int i = 0; i < 3; ++i)
                acc[i][j] += qv[i].x * kv.x + qv[i].y * kv.y + qv[i].z * kv.z + qv[i].w * kv.w;
        }
    }
    // write exp(scale*s) into sP
    #pragma unroll
    for (int i = 0; i < 3; ++i) {
        int u = 3 * ty + i;
        if (u < NTOP_) {
            #pragma unroll
            for (int j = 0; j < 8; ++j)
                sP[u * PSTRIDE + tx + 16 * j] = __expf(acc[i][j] * SCALE);
        }
    }
    __syncthreads();

    // load V tile into sKV (overwrite K)
    #pragma unroll
    for (int j = 0; j < 8; ++j) {
        int i = tid + 256 * j;
        int r = i >> 4, d4 = i & 15;
        float4 val = *(const float4*)(v + (((long)(b * L_ + key0 + r)) * H_ + h) * D_ + 4 * d4);
        *(float4*)(sKV + r * QSTRIDE + 4 * d4) = val;
    }
    __syncthreads();

    // partial l per query: one thread per u sums its sP row, atomic to global
    if (tid < NTOP_) {
        float s = 0.f;
        #pragma unroll 8
        for (int k4 = 0; k4 < 32; ++k4) {
            float4 e = *(const float4*)(sP + tid * PSTRIDE + 4 * k4);
            s += e.x + e.y + e.z + e.w;
        }
        atomicAdd(pl + bh * NTOP_ + tid, s);
    }

    // PV phase: thread (uy,dx) computes u = 3uy+i (i<3) x d = 4dx..4dx+3
    int dx = tid & 15, uy = tid >> 4;
    float o[3][4];
    #pragma unroll
    for (int i = 0; i < 3; ++i)
        #pragma unroll
        for (int c = 0; c < 4; ++c) o[i][c] = 0.f;

    #pragma unroll 2
    for (int k4 = 0; k4 < 32; ++k4) {
        float pa[3][4];
        #pragma unroll
        for (int i = 0; i < 3; ++i)
            *(float4*)pa[i] = *(const float4*)(sP + (3 * uy + i) * PSTRIDE + 4 * k4);
        #pragma unroll
        for (int c = 0; c < 4; ++c) {
            float4 vr = *(const float4*)(sKV + (4 * k4 + c) * QSTRIDE + 4 * dx);
            #pragma unroll
            for (int i = 0; i < 3; ++i) {
                o[i][0] += pa[i][c] * vr.x;
                o[i][1] += pa[i][c] * vr.y;
                o[i][2] += pa[i][c] * vr.z;
                o[i][3] += pa[i][c] * vr.w;
            }
        }
    }
    #pragma unroll
    for (int i = 0; i < 3; ++i) {
        int u = 3 * uy + i;
        if (u < NTOP_) {
            int lq = sTop[u];
            float* dst = out + (((long)(b * L_ + lq)) * H_ + h) * D_ + 4 * dx;
            atomicAdd(dst + 0, o[i][0]);
            atomicAdd(dst + 1, o[i][1]);
            atomicAdd(dst + 2, o[i][2]);
            atomicAdd(dst + 3, o[i][3]);
        }
    }
}

// ---------------- K4: normalize selected rows by total l ----------------
__global__ __launch_bounds__(64) void normalize_kernel(
    const int* __restrict__ topIdx, const float* __restrict__ pl,
    float* __restrict__ out) {
    int u = blockIdx.x, bh = blockIdx.y;
    int b = bh >> 3, h = bh & 7;
    int lq = topIdx[bh * NTOP_ + u];
    float inv = 1.0f / pl[bh * NTOP_ + u];
    int d = threadIdx.x;
    out[(((long)(b * L_ + lq)) * H_ + h) * D_ + d] *= inv;
}

extern "C" void kernel_launch(void* const* d_in, const int* in_sizes, int n_in,
                              void* d_out, int out_size, void* d_ws, size_t ws_size,
                              hipStream_t stream) {
    const float* q = (const float*)d_in[0];
    const float* k = (const float*)d_in[1];
    const float* v = (const float*)d_in[2];
    // d_in[3] = attn_mask (unused)
    const int* samp = (const int*)d_in[4];
    float* out = (float*)d_out;

    char* ws = (char*)d_ws;
    float* M      = (float*)ws;                                   // 512 KB
    int*   topIdx = (int*)(ws + (size_t)B_ * H_ * L_ * sizeof(float));
    float* pl     = (float*)(ws + (size_t)B_ * H_ * L_ * sizeof(float)
                                 + (size_t)B_ * H_ * NTOP_ * sizeof(int));

    hipMemsetAsync(d_out, 0, (size_t)out_size * sizeof(float), stream);
    hipMemsetAsync(pl, 0, (size_t)B_ * H_ * NTOP_ * sizeof(float), stream);

    compute_M_kernel<<<4096, 256, 0, stream>>>(q, k, samp, M);

    topk_kernel<<<B_ * H_, 256, 0, stream>>>(M, topIdx);

    attn_strip_kernel<<<SPLITS * B_ * H_, 256, 0, stream>>>(q, k, v, topIdx, out, pl);

    dim3 gn(NTOP_, B_ * H_);
    normalize_kernel<<<gn, 64, 0, stream>>>(topIdx, pl, out);
}

// Round 3
// 208.739 us; speedup vs baseline: 1.8995x; 1.1468x over previous
//
#include <hip/hip_runtime.h>
#include <math.h>

// Problem constants (B,L,H,D) = (2,4096,8,64); sample_k = n_top = 45
#define B_ 2
#define L_ 4096
#define H_ 8
#define D_ 64
#define S_ 45
#define NTOP_ 45
#define SCALE 0.125f  // 1/sqrt(64)
#define TKEYS 128     // keys per tile

// ---------------- K1: sparsity measure M = max_s(q.k_s) - sum_s/L ----------------
// One wave handles 4 queries; 16 lanes per query, each lane a float4 of D.
// Sample indices staged in LDS so the only global dependent load is the K gather.
__global__ __launch_bounds__(256) void compute_M_kernel(
    const float* __restrict__ q, const float* __restrict__ k,
    const int* __restrict__ samp, float* __restrict__ M) {
    __shared__ int sIdx[16 * S_];  // 720 ints
    int tid = threadIdx.x;
    int g   = blockIdx.x;           // 0..4095
    int xcd = g & 7;
    int s0  = g >> 3;               // 0..511
    int bh  = xcd + 8 * (s0 >> 8);  // 2 bh per XCD -> K slice stays L2-resident
    int chunk = s0 & 255;

    const int* sbase = samp + (long)chunk * (16 * S_);
    for (int i = tid; i < 16 * S_; i += 256) sIdx[i] = sbase[i];
    __syncthreads();

    int wave = tid >> 6, lane = tid & 63;
    int sub = lane >> 4, l16 = lane & 15;
    int qi = wave * 4 + sub;        // query within block (== l & 15)
    int l  = chunk * 16 + qi;
    int b = bh >> 3, h = bh & 7;

    const float* kb = k + ((long)b * L_ * H_ + h) * (long)D_;  // + idx*H_*D_
    float4 qf = ((const float4*)(q + (((long)(b * L_ + l)) * H_ + h) * D_))[l16];

    float vmax = -INFINITY, vsum = 0.f;
    #pragma unroll 9
    for (int s = 0; s < S_; ++s) {
        int idx = sIdx[qi * S_ + s];
        float4 kf = ((const float4*)(kb + (long)idx * (H_ * D_)))[l16];
        float p = qf.x * kf.x + qf.y * kf.y + qf.z * kf.z + qf.w * kf.w;
        p += __shfl_xor(p, 1, 64);
        p += __shfl_xor(p, 2, 64);
        p += __shfl_xor(p, 4, 64);
        p += __shfl_xor(p, 8, 64);
        vmax = fmaxf(vmax, p);
        vsum += p;
    }
    if (l16 == 0) M[(long)bh * L_ + l] = vmax - vsum * (1.0f / (float)L_);
}

// ---------------- K2: top-45 of M per (b,h), register-cached iterative argmax ----------------
__global__ __launch_bounds__(256) void topk_kernel(
    const float* __restrict__ M, int* __restrict__ topIdx) {
    __shared__ float rv[4];
    __shared__ int   ri[4];
    __shared__ int   sFi;
    int bh  = blockIdx.x;
    int tid = threadIdx.x;
    const float* row = M + (long)bh * L_;

    float val[16];
    #pragma unroll
    for (int j = 0; j < 16; ++j) val[j] = row[tid + 256 * j];

    // cached local argmax (ascending j => lowest-index tie-break within thread)
    float bv = -INFINITY; int bi = 0x7fffffff;
    #pragma unroll
    for (int j = 0; j < 16; ++j) {
        if (val[j] > bv) { bv = val[j]; bi = tid + 256 * j; }
    }

    for (int t = 0; t < NTOP_; ++t) {
        float mv = bv; int mi = bi;
        #pragma unroll
        for (int off = 1; off < 64; off <<= 1) {
            float ov = __shfl_xor(mv, off, 64);
            int   oi = __shfl_xor(mi, off, 64);
            if (ov > mv || (ov == mv && oi < mi)) { mv = ov; mi = oi; }
        }
        int w = tid >> 6;
        if ((tid & 63) == 0) { rv[w] = mv; ri[w] = mi; }
        __syncthreads();
        if (tid == 0) {
            float fv = rv[0]; int fi = ri[0];
            #pragma unroll
            for (int w2 = 1; w2 < 4; ++w2) {
                if (rv[w2] > fv || (rv[w2] == fv && ri[w2] < fi)) { fv = rv[w2]; fi = ri[w2]; }
            }
            topIdx[bh * NTOP_ + t] = fi;
            sFi = fi;
        }
        __syncthreads();
        int fi = sFi;
        if ((fi & 255) == tid) {   // winner thread: kill the value, rescan 16 regs
            int jkill = fi >> 8;
            #pragma unroll
            for (int j = 0; j < 16; ++j) if (j == jkill) val[j] = -INFINITY;
            bv = -INFINITY; bi = 0x7fffffff;
            #pragma unroll
            for (int j = 0; j < 16; ++j) {
                if (val[j] > bv) { bv = val[j]; bi = tid + 256 * j; }
            }
        }
    }
}

// ---------------- K3: key-strip attention, partial (Sum e*v, Sum e) per split ----------------
#define QSTRIDE 68    // padded LDS row stride for Q and K/V tiles (floats)
#define PSTRIDE 132   // padded LDS row stride for P (floats)
__global__ __launch_bounds__(256, 2) void attn_strip_kernel(
    const float* __restrict__ q, const float* __restrict__ k,
    const float* __restrict__ v, const int* __restrict__ topIdx,
    float* __restrict__ pOut, float* __restrict__ plPart,
    int nsplit, int ntiles) {
    __shared__ int   sTop[48];
    __shared__ float sQ[48 * QSTRIDE];     // 13.1 KB
    __shared__ float sKV[TKEYS * QSTRIDE]; // 34.8 KB (K, then V)
    __shared__ float sP[48 * PSTRIDE];     // 25.3 KB

    int g = blockIdx.x;
    int xcd = g & 7;
    int s0 = g >> 3;                  // 0 .. nsplit*2-1
    int grp = s0 / nsplit;            // 0..1
    int bh = xcd + 8 * grp;
    int split = s0 - grp * nsplit;
    int b = bh >> 3, h = bh & 7;
    int tid = threadIdx.x;

    if (tid < 48) sTop[tid] = (tid < NTOP_) ? topIdx[bh * NTOP_ + tid] : 0;
    __syncthreads();

    // load Q: 45 rows x 16 float4 (rows 45..47 zero)
    for (int i = tid; i < 768; i += 256) {
        int u = i >> 4, d4 = i & 15;
        float4 val = make_float4(0.f, 0.f, 0.f, 0.f);
        if (u < NTOP_) {
            int lq = sTop[u];
            val = *(const float4*)(q + (((long)(b * L_ + lq)) * H_ + h) * D_ + 4 * d4);
        }
        *(float4*)(sQ + u * QSTRIDE + 4 * d4) = val;
    }

    int tx = tid & 15, ty = tid >> 4;   // S phase: u = 3ty+i x keys tx+16j
    int dx = tid & 15, uy = tid >> 4;   // PV phase: u = 3uy+i x d = 4dx..
    float o[3][4];
    float ls[3];
    #pragma unroll
    for (int i = 0; i < 3; ++i) {
        ls[i] = 0.f;
        #pragma unroll
        for (int c = 0; c < 4; ++c) o[i][c] = 0.f;
    }

    #pragma unroll 1
    for (int tile = 0; tile < ntiles; ++tile) {
        int key0 = (split * ntiles + tile) * TKEYS;
        __syncthreads();  // prev PV (or Q-load) done before sKV overwrite
        #pragma unroll
        for (int j = 0; j < 8; ++j) {
            int i = tid + 256 * j;
            int r = i >> 4, d4 = i & 15;
            float4 val = *(const float4*)(k + (((long)(b * L_ + key0 + r)) * H_ + h) * D_ + 4 * d4);
            *(float4*)(sKV + r * QSTRIDE + 4 * d4) = val;
        }
        __syncthreads();

        float acc[3][8];
        #pragma unroll
        for (int i = 0; i < 3; ++i)
            #pragma unroll
            for (int j = 0; j < 8; ++j) acc[i][j] = 0.f;

        #pragma unroll 4
        for (int d4 = 0; d4 < 16; ++d4) {
            float4 qv[3];
            #pragma unroll
            for (int i = 0; i < 3; ++i)
                qv[i] = *(const float4*)(sQ + (3 * ty + i) * QSTRIDE + 4 * d4);
            #pragma unroll
            for (int j = 0; j < 8; ++j) {
                float4 kv = *(const float4*)(sKV + (tx + 16 * j) * QSTRIDE + 4 * d4);
                #pragma unroll
                for (int i = 0; i < 3; ++i)
                    acc[i][j] += qv[i].x * kv.x + qv[i].y * kv.y + qv[i].z * kv.z + qv[i].w * kv.w;
            }
        }
        #pragma unroll
        for (int i = 0; i < 3; ++i) {
            #pragma unroll
            for (int j = 0; j < 8; ++j)
                sP[(3 * ty + i) * PSTRIDE + tx + 16 * j] = __expf(acc[i][j] * SCALE);
        }
        __syncthreads();  // S done (K reads + P writes) before V overwrite

        #pragma unroll
        for (int j = 0; j < 8; ++j) {
            int i = tid + 256 * j;
            int r = i >> 4, d4 = i & 15;
            float4 val = *(const float4*)(v + (((long)(b * L_ + key0 + r)) * H_ + h) * D_ + 4 * d4);
            *(float4*)(sKV + r * QSTRIDE + 4 * d4) = val;
        }
        __syncthreads();

        #pragma unroll 2
        for (int k4 = 0; k4 < 32; ++k4) {
            float pa[3][4];
            #pragma unroll
            for (int i = 0; i < 3; ++i)
                *(float4*)pa[i] = *(const float4*)(sP + (3 * uy + i) * PSTRIDE + 4 * k4);
            #pragma unroll
            for (int c = 0; c < 4; ++c) {
                float4 vr = *(const float4*)(sKV + (4 * k4 + c) * QSTRIDE + 4 * dx);
                #pragma unroll
                for (int i = 0; i < 3; ++i) {
                    o[i][0] += pa[i][c] * vr.x;
                    o[i][1] += pa[i][c] * vr.y;
                    o[i][2] += pa[i][c] * vr.z;
                    o[i][3] += pa[i][c] * vr.w;
                    ls[i]   += pa[i][c];
                }
            }
        }
    }

    // store partials (contention-free)
    #pragma unroll
    for (int i = 0; i < 3; ++i) {
        int u = 3 * uy + i;
        if (u < NTOP_) {
            long base = ((long)(split * 16 + bh) * NTOP_ + u) * D_;
            *(float4*)(pOut + base + 4 * dx) = make_float4(o[i][0], o[i][1], o[i][2], o[i][3]);
            if (dx == 0) plPart[(long)(split * 16 + bh) * NTOP_ + u] = ls[i];
        }
    }
}

// ---------------- K4: reduce partials across splits, normalize, scatter to out ----------------
__global__ __launch_bounds__(64) void reduce_norm_kernel(
    const int* __restrict__ topIdx, const float* __restrict__ pOut,
    const float* __restrict__ plPart, float* __restrict__ out, int nsplit) {
    int u = blockIdx.x, bh = blockIdx.y;
    int b = bh >> 3, h = bh & 7;
    int d = threadIdx.x;
    float acc = 0.f, lsum = 0.f;
    for (int s = 0; s < nsplit; ++s) {
        acc  += pOut[((long)(s * 16 + bh) * NTOP_ + u) * D_ + d];
        lsum += plPart[(long)(s * 16 + bh) * NTOP_ + u];
    }
    int lq = topIdx[bh * NTOP_ + u];
    out[(((long)(b * L_ + lq)) * H_ + h) * D_ + d] = acc / lsum;
}

extern "C" void kernel_launch(void* const* d_in, const int* in_sizes, int n_in,
                              void* d_out, int out_size, void* d_ws, size_t ws_size,
                              hipStream_t stream) {
    const float* q = (const float*)d_in[0];
    const float* k = (const float*)d_in[1];
    const float* v = (const float*)d_in[2];
    // d_in[3] = attn_mask (unused)
    const int* samp = (const int*)d_in[4];
    float* out = (float*)d_out;

    char* ws = (char*)d_ws;
    const size_t mBytes   = (size_t)B_ * H_ * L_ * sizeof(float);   // 512 KB
    const size_t topBytes = (size_t)B_ * H_ * NTOP_ * sizeof(int);  // 2880 B
    const size_t plBytes  = (size_t)32 * 16 * NTOP_ * sizeof(float);// reserve for max splits
    float* M      = (float*)ws;
    int*   topIdx = (int*)(ws + mBytes);
    float* plPart = (float*)(ws + mBytes + topBytes);
    float* pOut   = (float*)(ws + mBytes + topBytes + plBytes);

    // pick split count that fits the workspace
    int nsplit = 32;
    while (nsplit > 1) {
        size_t need = mBytes + topBytes + plBytes +
                      (size_t)nsplit * 16 * NTOP_ * D_ * sizeof(float);
        if (need <= ws_size) break;
        nsplit >>= 1;
    }
    int ntiles = 32 / nsplit;

    hipMemsetAsync(d_out, 0, (size_t)out_size * sizeof(float), stream);

    compute_M_kernel<<<4096, 256, 0, stream>>>(q, k, samp, M);

    topk_kernel<<<B_ * H_, 256, 0, stream>>>(M, topIdx);

    attn_strip_kernel<<<nsplit * B_ * H_, 256, 0, stream>>>(
        q, k, v, topIdx, pOut, plPart, nsplit, ntiles);

    dim3 gn(NTOP_, B_ * H_);
    reduce_norm_kernel<<<gn, 64, 0, stream>>>(topIdx, pOut, plPart, out, nsplit);
}

// Round 4
// 186.631 us; speedup vs baseline: 2.1246x; 1.1185x over previous
//
#include <hip/hip_runtime.h>
#include <math.h>

// Problem constants (B,L,H,D) = (2,4096,8,64); sample_k = n_top = 45
#define B_ 2
#define L_ 4096
#define H_ 8
#define D_ 64
#define S_ 45
#define NTOP_ 45
#define SCALE 0.125f  // 1/sqrt(64)
#define TKEYS 128     // keys per tile

// ---------------- K1: sparsity measure M = max_s(q.k_s) - sum_s/L ----------------
// 4 lanes per query (16 queries/wave): lane dots a 16-elem slice, 2 shfls reduce.
// Sample indices staged in LDS; XCD swizzle keeps each XCD's K slice L2-resident.
__global__ __launch_bounds__(256) void compute_M_kernel(
    const float* __restrict__ q, const float* __restrict__ k,
    const int* __restrict__ samp, float* __restrict__ M) {
    __shared__ int sIdx[64 * S_];   // 2880 ints = 11.5 KB
    int tid = threadIdx.x;
    int g   = blockIdx.x;           // 0..1023
    int xcd = g & 7;
    int s0  = g >> 3;               // 0..127
    int bh  = xcd + 8 * (s0 >> 6);  // 2 bh per XCD
    int c64 = s0 & 63;              // chunk of 64 queries
    int b = bh >> 3, h = bh & 7;
    int l0 = c64 * 64;

    const int* sbase = samp + (long)l0 * S_;
    for (int i = tid; i < 64 * S_; i += 256) sIdx[i] = sbase[i];
    __syncthreads();

    int lane = tid & 63, wave = tid >> 6;
    int l4 = lane & 3;              // which 16-elem slice of D
    int q4 = lane >> 2;             // query within wave (0..15)
    int qi = wave * 16 + q4;        // query within block (0..63)
    int l  = l0 + qi;

    const float4* qrow = (const float4*)(q + (((long)(b * L_ + l)) * H_ + h) * D_);
    float4 qf0 = qrow[l4 * 4 + 0], qf1 = qrow[l4 * 4 + 1];
    float4 qf2 = qrow[l4 * 4 + 2], qf3 = qrow[l4 * 4 + 3];

    const float* kb = k + ((long)b * L_ * H_ + h) * (long)D_;
    float vmax = -INFINITY, vsum = 0.f;
    #pragma unroll 3
    for (int s = 0; s < S_; ++s) {
        int idx = sIdx[qi * S_ + s];
        const float4* krow = (const float4*)(kb + (long)idx * (H_ * D_));
        float4 k0 = krow[l4 * 4 + 0], k1 = krow[l4 * 4 + 1];
        float4 k2 = krow[l4 * 4 + 2], k3 = krow[l4 * 4 + 3];
        float p = qf0.x * k0.x + qf0.y * k0.y + qf0.z * k0.z + qf0.w * k0.w
                + qf1.x * k1.x + qf1.y * k1.y + qf1.z * k1.z + qf1.w * k1.w
                + qf2.x * k2.x + qf2.y * k2.y + qf2.z * k2.z + qf2.w * k2.w
                + qf3.x * k3.x + qf3.y * k3.y + qf3.z * k3.z + qf3.w * k3.w;
        p += __shfl_xor(p, 1, 64);
        p += __shfl_xor(p, 2, 64);
        vmax = fmaxf(vmax, p);
        vsum += p;
    }
    if (l4 == 0) M[(long)bh * L_ + l] = vmax - vsum * (1.0f / (float)L_);
}

// ---------------- K2: top-45 set per (b,h) via byte-radix select ----------------
// Output order is arbitrary: reference scatters context_in_q[u] to row M_top[u],
// so only the selected SET matters. Tie-break at threshold = lowest index.
__global__ __launch_bounds__(256) void topk_kernel(
    const float* __restrict__ M, int* __restrict__ topIdx) {
    __shared__ unsigned int hist[256];
    __shared__ unsigned int suf[257];
    __shared__ unsigned int wsum[4];
    __shared__ int sBin, sRemain, sCnt, sTieCnt;
    __shared__ int tie[64];

    int bh = blockIdx.x, tid = threadIdx.x;
    int lane = tid & 63, wave = tid >> 6;
    const float* row = M + (long)bh * L_;

    unsigned int key[16];
    #pragma unroll
    for (int j = 0; j < 16; ++j) {
        unsigned int bts = __float_as_uint(row[tid + 256 * j]);
        key[j] = bts ^ ((unsigned int)((int)bts >> 31) | 0x80000000u);
    }

    unsigned int prefix = 0, pmask = 0;
    int remain = NTOP_;
    #pragma unroll 1
    for (int pass = 3; pass >= 0; --pass) {
        int shift = pass * 8;
        hist[tid] = 0;
        __syncthreads();
        #pragma unroll
        for (int j = 0; j < 16; ++j) {
            if ((key[j] & pmask) == prefix)
                atomicAdd(&hist[(key[j] >> shift) & 255u], 1u);
        }
        __syncthreads();
        // suffix sum suf[t] = sum_{i>=t} hist[i]: wave scan + cross-wave combine
        unsigned int s = hist[tid];
        #pragma unroll
        for (int off = 1; off < 64; off <<= 1) {
            unsigned int o = __shfl_down(s, off, 64);
            if (lane + off < 64) s += o;
        }
        if (lane == 0) wsum[wave] = s;
        __syncthreads();
        unsigned int add = 0;
        for (int w = wave + 1; w < 4; ++w) add += wsum[w];
        s += add;
        suf[tid] = s;
        if (tid == 0) suf[256] = 0;
        __syncthreads();
        if (suf[tid] >= (unsigned int)remain && suf[tid + 1] < (unsigned int)remain) {
            sBin = tid;
            sRemain = remain - (int)suf[tid + 1];
        }
        __syncthreads();
        prefix |= ((unsigned int)sBin) << shift;
        pmask  |= 0xFFu << shift;
        remain  = sRemain;
        __syncthreads();
    }

    if (tid == 0) { sCnt = 0; sTieCnt = 0; }
    __syncthreads();
    int* outRow = topIdx + bh * NTOP_;
    #pragma unroll
    for (int j = 0; j < 16; ++j) {
        int idx = tid + 256 * j;
        if (key[j] > prefix) {
            int pos = atomicAdd(&sCnt, 1);
            outRow[pos] = idx;
        } else if (key[j] == prefix) {
            int tp = atomicAdd(&sTieCnt, 1);
            if (tp < 64) tie[tp] = idx;
        }
    }
    __syncthreads();
    if (tid == 0) {
        int base = sCnt;   // == NTOP_ - remain
        int tc = sTieCnt < 64 ? sTieCnt : 64;
        for (int t = 0; t < remain; ++t) {
            int mi = 0x7fffffff, mj = 0;
            for (int j2 = 0; j2 < tc; ++j2)
                if (tie[j2] < mi) { mi = tie[j2]; mj = j2; }
            outRow[base + t] = mi;
            tie[mj] = 0x7fffffff;
        }
    }
}

// ---------------- K3: key-strip attention, partial (Sum e*v, Sum e) per split ----------------
#define QSTRIDE 68    // padded LDS row stride for Q and K/V tiles (floats)
#define PSTRIDE 132   // padded LDS row stride for P (floats)
__global__ __launch_bounds__(256, 2) void attn_strip_kernel(
    const float* __restrict__ q, const float* __restrict__ k,
    const float* __restrict__ v, const int* __restrict__ topIdx,
    float* __restrict__ pOut, float* __restrict__ plPart,
    int nsplit, int ntiles) {
    __shared__ int   sTop[48];
    __shared__ float sQ[48 * QSTRIDE];     // 13.1 KB
    __shared__ float sKV[TKEYS * QSTRIDE]; // 34.8 KB (K, then V)
    __shared__ float sP[48 * PSTRIDE];     // 25.3 KB

    int g = blockIdx.x;
    int xcd = g & 7;
    int s0 = g >> 3;                  // 0 .. nsplit*2-1
    int grp = s0 / nsplit;            // 0..1
    int bh = xcd + 8 * grp;
    int split = s0 - grp * nsplit;
    int b = bh >> 3, h = bh & 7;
    int tid = threadIdx.x;

    if (tid < 48) sTop[tid] = (tid < NTOP_) ? topIdx[bh * NTOP_ + tid] : 0;
    __syncthreads();

    // load Q: 45 rows x 16 float4 (rows 45..47 zero)
    for (int i = tid; i < 768; i += 256) {
        int u = i >> 4, d4 = i & 15;
        float4 val = make_float4(0.f, 0.f, 0.f, 0.f);
        if (u < NTOP_) {
            int lq = sTop[u];
            val = *(const float4*)(q + (((long)(b * L_ + lq)) * H_ + h) * D_ + 4 * d4);
        }
        *(float4*)(sQ + u * QSTRIDE + 4 * d4) = val;
    }

    int tx = tid & 15, ty = tid >> 4;   // S phase: u = 3ty+i x keys tx+16j
    int dx = tid & 15, uy = tid >> 4;   // PV phase: u = 3uy+i x d = 4dx..
    float o[3][4];
    float ls[3];
    #pragma unroll
    for (int i = 0; i < 3; ++i) {
        ls[i] = 0.f;
        #pragma unroll
        for (int c = 0; c < 4; ++c) o[i][c] = 0.f;
    }

    #pragma unroll 1
    for (int tile = 0; tile < ntiles; ++tile) {
        int key0 = (split * ntiles + tile) * TKEYS;
        __syncthreads();  // prev PV (or Q-load) done before sKV overwrite
        #pragma unroll
        for (int j = 0; j < 8; ++j) {
            int i = tid + 256 * j;
            int r = i >> 4, d4 = i & 15;
            float4 val = *(const float4*)(k + (((long)(b * L_ + key0 + r)) * H_ + h) * D_ + 4 * d4);
            *(float4*)(sKV + r * QSTRIDE + 4 * d4) = val;
        }
        __syncthreads();

        float acc[3][8];
        #pragma unroll
        for (int i = 0; i < 3; ++i)
            #pragma unroll
            for (int j = 0; j < 8; ++j) acc[i][j] = 0.f;

        #pragma unroll 4
        for (int d4 = 0; d4 < 16; ++d4) {
            float4 qv[3];
            #pragma unroll
            for (int i = 0; i < 3; ++i)
                qv[i] = *(const float4*)(sQ + (3 * ty + i) * QSTRIDE + 4 * d4);
            #pragma unroll
            for (int j = 0; j < 8; ++j) {
                float4 kv = *(const float4*)(sKV + (tx + 16 * j) * QSTRIDE + 4 * d4);
                #pragma unroll
                for (int i = 0; i < 3; ++i)
                    acc[i][j] += qv[i].x * kv.x + qv[i].y * kv.y + qv[i].z * kv.z + qv[i].w * kv.w;
            }
        }
        #pragma unroll
        for (int i = 0; i < 3; ++i) {
            #pragma unroll
            for (int j = 0; j < 8; ++j)
                sP[(3 * ty + i) * PSTRIDE + tx + 16 * j] = __expf(acc[i][j] * SCALE);
        }
        __syncthreads();  // S done (K reads + P writes) before V overwrite

        #pragma unroll
        for (int j = 0; j < 8; ++j) {
            int i = tid + 256 * j;
            int r = i >> 4, d4 = i & 15;
            float4 val = *(const float4*)(v + (((long)(b * L_ + key0 + r)) * H_ + h) * D_ + 4 * d4);
            *(float4*)(sKV + r * QSTRIDE + 4 * d4) = val;
        }
        __syncthreads();

        #pragma unroll 2
        for (int k4 = 0; k4 < 32; ++k4) {
            float pa[3][4];
            #pragma unroll
            for (int i = 0; i < 3; ++i)
                *(float4*)pa[i] = *(const float4*)(sP + (3 * uy + i) * PSTRIDE + 4 * k4);
            #pragma unroll
            for (int c = 0; c < 4; ++c) {
                float4 vr = *(const float4*)(sKV + (4 * k4 + c) * QSTRIDE + 4 * dx);
                #pragma unroll
                for (int i = 0; i < 3; ++i) {
                    o[i][0] += pa[i][c] * vr.x;
                    o[i][1] += pa[i][c] * vr.y;
                    o[i][2] += pa[i][c] * vr.z;
                    o[i][3] += pa[i][c] * vr.w;
                    ls[i]   += pa[i][c];
                }
            }
        }
    }

    // store partials (contention-free)
    #pragma unroll
    for (int i = 0; i < 3; ++i) {
        int u = 3 * uy + i;
        if (u < NTOP_) {
            long base = ((long)(split * 16 + bh) * NTOP_ + u) * D_;
            *(float4*)(pOut + base + 4 * dx) = make_float4(o[i][0], o[i][1], o[i][2], o[i][3]);
            if (dx == 0) plPart[(long)(split * 16 + bh) * NTOP_ + u] = ls[i];
        }
    }
}

// ---------------- K4: reduce partials across splits, normalize, scatter to out ----------------
__global__ __launch_bounds__(64) void reduce_norm_kernel(
    const int* __restrict__ topIdx, const float* __restrict__ pOut,
    const float* __restrict__ plPart, float* __restrict__ out, int nsplit) {
    int u = blockIdx.x, bh = blockIdx.y;
    int b = bh >> 3, h = bh & 7;
    int d = threadIdx.x;
    float acc = 0.f, lsum = 0.f;
    for (int s = 0; s < nsplit; ++s) {
        acc  += pOut[((long)(s * 16 + bh) * NTOP_ + u) * D_ + d];
        lsum += plPart[(long)(s * 16 + bh) * NTOP_ + u];
    }
    int lq = topIdx[bh * NTOP_ + u];
    out[(((long)(b * L_ + lq)) * H_ + h) * D_ + d] = acc / lsum;
}

extern "C" void kernel_launch(void* const* d_in, const int* in_sizes, int n_in,
                              void* d_out, int out_size, void* d_ws, size_t ws_size,
                              hipStream_t stream) {
    const float* q = (const float*)d_in[0];
    const float* k = (const float*)d_in[1];
    const float* v = (const float*)d_in[2];
    // d_in[3] = attn_mask (unused)
    const int* samp = (const int*)d_in[4];
    float* out = (float*)d_out;

    char* ws = (char*)d_ws;
    const size_t mBytes   = (size_t)B_ * H_ * L_ * sizeof(float);   // 512 KB
    const size_t topBytes = (size_t)B_ * H_ * NTOP_ * sizeof(int);  // 2880 B
    const size_t plBytes  = (size_t)32 * 16 * NTOP_ * sizeof(float);
    float* M      = (float*)ws;
    int*   topIdx = (int*)(ws + mBytes);
    float* plPart = (float*)(ws + mBytes + topBytes);
    float* pOut   = (float*)(ws + mBytes + topBytes + plBytes);

    // pick split count that fits the workspace
    int nsplit = 32;
    while (nsplit > 1) {
        size_t need = mBytes + topBytes + plBytes +
                      (size_t)nsplit * 16 * NTOP_ * D_ * sizeof(float);
        if (need <= ws_size) break;
        nsplit >>= 1;
    }
    int ntiles = 32 / nsplit;

    hipMemsetAsync(d_out, 0, (size_t)out_size * sizeof(float), stream);

    compute_M_kernel<<<1024, 256, 0, stream>>>(q, k, samp, M);

    topk_kernel<<<B_ * H_, 256, 0, stream>>>(M, topIdx);

    attn_strip_kernel<<<nsplit * B_ * H_, 256, 0, stream>>>(
        q, k, v, topIdx, pOut, plPart, nsplit, ntiles);

    dim3 gn(NTOP_, B_ * H_);
    reduce_norm_kernel<<<gn, 64, 0, stream>>>(topIdx, pOut, plPart, out, nsplit);
}

// Round 5
// 174.217 us; speedup vs baseline: 2.2759x; 1.0713x over previous
//
#include <hip/hip_runtime.h>
#include <math.h>

// Problem constants (B,L,H,D) = (2,4096,8,64); sample_k = n_top = 45
#define B_ 2
#define L_ 4096
#define H_ 8
#define D_ 64
#define S_ 45
#define NTOP_ 45
#define SCALE 0.125f  // 1/sqrt(64)
#define TKEYS 128     // keys per tile

// ---------------- K1: sparsity measure M = max_s(q.k_s) - sum_s/L ----------------
// 4 lanes per query (16 queries/wave). TRANSPOSED fragment: lane l4 holds float4s
// {l4, 4+l4, 8+l4, 12+l4} so each vmem instruction's 4-lane cluster reads ONE
// contiguous fully-utilized 64B cache line per query (16 lines/wave-instr).
__global__ __launch_bounds__(256) void compute_M_kernel(
    const float* __restrict__ q, const float* __restrict__ k,
    const int* __restrict__ samp, float* __restrict__ M) {
    __shared__ int sIdx[64 * S_];   // 2880 ints = 11.5 KB
    int tid = threadIdx.x;
    int g   = blockIdx.x;           // 0..1023
    int xcd = g & 7;
    int s0  = g >> 3;               // 0..127
    int bh  = xcd + 8 * (s0 >> 6);  // 2 bh per XCD -> K slice stays L2-resident
    int c64 = s0 & 63;              // chunk of 64 queries
    int b = bh >> 3, h = bh & 7;
    int l0 = c64 * 64;

    const int* sbase = samp + (long)l0 * S_;
    for (int i = tid; i < 64 * S_; i += 256) sIdx[i] = sbase[i];
    __syncthreads();

    int lane = tid & 63, wave = tid >> 6;
    int l4 = lane & 3;              // cluster lane
    int q4 = lane >> 2;             // query within wave (0..15)
    int qi = wave * 16 + q4;        // query within block (0..63)
    int l  = l0 + qi;

    const float4* qrow = (const float4*)(q + (((long)(b * L_ + l)) * H_ + h) * D_);
    float4 qf0 = qrow[l4], qf1 = qrow[4 + l4], qf2 = qrow[8 + l4], qf3 = qrow[12 + l4];

    const float* kb = k + ((long)b * L_ * H_ + h) * (long)D_;
    float vmax = -INFINITY, vsum = 0.f;
    #pragma unroll 5
    for (int s = 0; s < S_; ++s) {
        int idx = sIdx[qi * S_ + s];
        const float4* krow = (const float4*)(kb + (long)idx * (H_ * D_));
        float4 k0 = krow[l4], k1 = krow[4 + l4], k2 = krow[8 + l4], k3 = krow[12 + l4];
        float p = qf0.x * k0.x + qf0.y * k0.y + qf0.z * k0.z + qf0.w * k0.w
                + qf1.x * k1.x + qf1.y * k1.y + qf1.z * k1.z + qf1.w * k1.w
                + qf2.x * k2.x + qf2.y * k2.y + qf2.z * k2.z + qf2.w * k2.w
                + qf3.x * k3.x + qf3.y * k3.y + qf3.z * k3.z + qf3.w * k3.w;
        p += __shfl_xor(p, 1, 64);
        p += __shfl_xor(p, 2, 64);
        vmax = fmaxf(vmax, p);
        vsum += p;
    }
    if (l4 == 0) M[(long)bh * L_ + l] = vmax - vsum * (1.0f / (float)L_);
}

// ---------------- K2: top-45 set per (b,h) via byte-radix select ----------------
// Output order is arbitrary: reference scatters context_in_q[u] to row M_top[u],
// so only the selected SET matters. Tie-break at threshold = lowest index.
__global__ __launch_bounds__(256) void topk_kernel(
    const float* __restrict__ M, int* __restrict__ topIdx) {
    __shared__ unsigned int hist[256];
    __shared__ unsigned int suf[257];
    __shared__ unsigned int wsum[4];
    __shared__ int sBin, sRemain, sCnt, sTieCnt;
    __shared__ int tie[64];

    int bh = blockIdx.x, tid = threadIdx.x;
    int lane = tid & 63, wave = tid >> 6;
    const float* row = M + (long)bh * L_;

    unsigned int key[16];
    #pragma unroll
    for (int j = 0; j < 16; ++j) {
        unsigned int bts = __float_as_uint(row[tid + 256 * j]);
        key[j] = bts ^ ((unsigned int)((int)bts >> 31) | 0x80000000u);
    }

    unsigned int prefix = 0, pmask = 0;
    int remain = NTOP_;
    #pragma unroll 1
    for (int pass = 3; pass >= 0; --pass) {
        int shift = pass * 8;
        hist[tid] = 0;
        __syncthreads();
        #pragma unroll
        for (int j = 0; j < 16; ++j) {
            if ((key[j] & pmask) == prefix)
                atomicAdd(&hist[(key[j] >> shift) & 255u], 1u);
        }
        __syncthreads();
        // suffix sum suf[t] = sum_{i>=t} hist[i]: wave scan + cross-wave combine
        unsigned int s = hist[tid];
        #pragma unroll
        for (int off = 1; off < 64; off <<= 1) {
            unsigned int o = __shfl_down(s, off, 64);
            if (lane + off < 64) s += o;
        }
        if (lane == 0) wsum[wave] = s;
        __syncthreads();
        unsigned int add = 0;
        for (int w = wave + 1; w < 4; ++w) add += wsum[w];
        s += add;
        suf[tid] = s;
        if (tid == 0) suf[256] = 0;
        __syncthreads();
        if (suf[tid] >= (unsigned int)remain && suf[tid + 1] < (unsigned int)remain) {
            sBin = tid;
            sRemain = remain - (int)suf[tid + 1];
        }
        __syncthreads();
        prefix |= ((unsigned int)sBin) << shift;
        pmask  |= 0xFFu << shift;
        remain  = sRemain;
        __syncthreads();
    }

    if (tid == 0) { sCnt = 0; sTieCnt = 0; }
    __syncthreads();
    int* outRow = topIdx + bh * NTOP_;
    #pragma unroll
    for (int j = 0; j < 16; ++j) {
        int idx = tid + 256 * j;
        if (key[j] > prefix) {
            int pos = atomicAdd(&sCnt, 1);
            outRow[pos] = idx;
        } else if (key[j] == prefix) {
            int tp = atomicAdd(&sTieCnt, 1);
            if (tp < 64) tie[tp] = idx;
        }
    }
    __syncthreads();
    if (tid == 0) {
        int base = sCnt;   // == NTOP_ - remain
        int tc = sTieCnt < 64 ? sTieCnt : 64;
        for (int t = 0; t < remain; ++t) {
            int mi = 0x7fffffff, mj = 0;
            for (int j2 = 0; j2 < tc; ++j2)
                if (tie[j2] < mi) { mi = tie[j2]; mj = j2; }
            outRow[base + t] = mi;
            tie[mj] = 0x7fffffff;
        }
    }
}

// ---------------- K3: key-strip attention, partial (Sum e*v, Sum e) per split ----------------
#define QSTRIDE 68    // padded LDS row stride for Q and K/V tiles (floats)
#define PSTRIDE 132   // padded LDS row stride for P (floats)
__global__ __launch_bounds__(256, 2) void attn_strip_kernel(
    const float* __restrict__ q, const float* __restrict__ k,
    const float* __restrict__ v, const int* __restrict__ topIdx,
    float* __restrict__ pOut, float* __restrict__ plPart,
    int nsplit, int ntiles) {
    __shared__ int   sTop[48];
    __shared__ float sQ[48 * QSTRIDE];     // 13.1 KB
    __shared__ float sKV[TKEYS * QSTRIDE]; // 34.8 KB (K, then V)
    __shared__ float sP[48 * PSTRIDE];     // 25.3 KB

    int g = blockIdx.x;
    int xcd = g & 7;
    int s0 = g >> 3;                  // 0 .. nsplit*2-1
    int grp = s0 / nsplit;            // 0..1
    int bh = xcd + 8 * grp;
    int split = s0 - grp * nsplit;
    int b = bh >> 3, h = bh & 7;
    int tid = threadIdx.x;

    if (tid < 48) sTop[tid] = (tid < NTOP_) ? topIdx[bh * NTOP_ + tid] : 0;
    __syncthreads();

    // load Q: 45 rows x 16 float4 (rows 45..47 zero)
    for (int i = tid; i < 768; i += 256) {
        int u = i >> 4, d4 = i & 15;
        float4 val = make_float4(0.f, 0.f, 0.f, 0.f);
        if (u < NTOP_) {
            int lq = sTop[u];
            val = *(const float4*)(q + (((long)(b * L_ + lq)) * H_ + h) * D_ + 4 * d4);
        }
        *(float4*)(sQ + u * QSTRIDE + 4 * d4) = val;
    }

    int tx = tid & 15, ty = tid >> 4;   // S phase: u = 3ty+i x keys tx+16j
    int dx = tid & 15, uy = tid >> 4;   // PV phase: u = 3uy+i x d = 4dx..
    float o[3][4];
    float ls[3];
    #pragma unroll
    for (int i = 0; i < 3; ++i) {
        ls[i] = 0.f;
        #pragma unroll
        for (int c = 0; c < 4; ++c) o[i][c] = 0.f;
    }

    #pragma unroll 1
    for (int tile = 0; tile < ntiles; ++tile) {
        int key0 = (split * ntiles + tile) * TKEYS;
        __syncthreads();  // prev PV (or Q-load) done before sKV overwrite
        #pragma unroll
        for (int j = 0; j < 8; ++j) {
            int i = tid + 256 * j;
            int r = i >> 4, d4 = i & 15;
            float4 val = *(const float4*)(k + (((long)(b * L_ + key0 + r)) * H_ + h) * D_ + 4 * d4);
            *(float4*)(sKV + r * QSTRIDE + 4 * d4) = val;
        }
        __syncthreads();

        float acc[3][8];
        #pragma unroll
        for (int i = 0; i < 3; ++i)
            #pragma unroll
            for (int j = 0; j < 8; ++j) acc[i][j] = 0.f;

        #pragma unroll 4
        for (int d4 = 0; d4 < 16; ++d4) {
            float4 qv[3];
            #pragma unroll
            for (int i = 0; i < 3; ++i)
                qv[i] = *(const float4*)(sQ + (3 * ty + i) * QSTRIDE + 4 * d4);
            #pragma unroll
            for (int j = 0; j < 8; ++j) {
                float4 kv = *(const float4*)(sKV + (tx + 16 * j) * QSTRIDE + 4 * d4);
                #pragma unroll
                for (int i = 0; i < 3; ++i)
                    acc[i][j] += qv[i].x * kv.x + qv[i].y * kv.y + qv[i].z * kv.z + qv[i].w * kv.w;
            }
        }
        #pragma unroll
        for (int i = 0; i < 3; ++i) {
            #pragma unroll
            for (int j = 0; j < 8; ++j)
                sP[(3 * ty + i) * PSTRIDE + tx + 16 * j] = __expf(acc[i][j] * SCALE);
        }
        __syncthreads();  // S done (K reads + P writes) before V overwrite

        #pragma unroll
        for (int j = 0; j < 8; ++j) {
            int i = tid + 256 * j;
            int r = i >> 4, d4 = i & 15;
            float4 val = *(const float4*)(v + (((long)(b * L_ + key0 + r)) * H_ + h) * D_ + 4 * d4);
            *(float4*)(sKV + r * QSTRIDE + 4 * d4) = val;
        }
        __syncthreads();

        #pragma unroll 2
        for (int k4 = 0; k4 < 32; ++k4) {
            float pa[3][4];
            #pragma unroll
            for (int i = 0; i < 3; ++i)
                *(float4*)pa[i] = *(const float4*)(sP + (3 * uy + i) * PSTRIDE + 4 * k4);
            #pragma unroll
            for (int c = 0; c < 4; ++c) {
                float4 vr = *(const float4*)(sKV + (4 * k4 + c) * QSTRIDE + 4 * dx);
                #pragma unroll
                for (int i = 0; i < 3; ++i) {
                    o[i][0] += pa[i][c] * vr.x;
                    o[i][1] += pa[i][c] * vr.y;
                    o[i][2] += pa[i][c] * vr.z;
                    o[i][3] += pa[i][c] * vr.w;
                    ls[i]   += pa[i][c];
                }
            }
        }
    }

    // store partials (contention-free)
    #pragma unroll
    for (int i = 0; i < 3; ++i) {
        int u = 3 * uy + i;
        if (u < NTOP_) {
            long base = ((long)(split * 16 + bh) * NTOP_ + u) * D_;
            *(float4*)(pOut + base + 4 * dx) = make_float4(o[i][0], o[i][1], o[i][2], o[i][3]);
            if (dx == 0) plPart[(long)(split * 16 + bh) * NTOP_ + u] = ls[i];
        }
    }
}

// ---------------- K4: reduce partials across splits, normalize, scatter to out ----------------
__global__ __launch_bounds__(64) void reduce_norm_kernel(
    const int* __restrict__ topIdx, const float* __restrict__ pOut,
    const float* __restrict__ plPart, float* __restrict__ out, int nsplit) {
    int u = blockIdx.x, bh = blockIdx.y;
    int b = bh >> 3, h = bh & 7;
    int d = threadIdx.x;
    float acc = 0.f, lsum = 0.f;
    for (int s = 0; s < nsplit; ++s) {
        acc  += pOut[((long)(s * 16 + bh) * NTOP_ + u) * D_ + d];
        lsum += plPart[(long)(s * 16 + bh) * NTOP_ + u];
    }
    int lq = topIdx[bh * NTOP_ + u];
    out[(((long)(b * L_ + lq)) * H_ + h) * D_ + d] = acc / lsum;
}

extern "C" void kernel_launch(void* const* d_in, const int* in_sizes, int n_in,
                              void* d_out, int out_size, void* d_ws, size_t ws_size,
                              hipStream_t stream) {
    const float* q = (const float*)d_in[0];
    const float* k = (const float*)d_in[1];
    const float* v = (const float*)d_in[2];
    // d_in[3] = attn_mask (unused)
    const int* samp = (const int*)d_in[4];
    float* out = (float*)d_out;

    char* ws = (char*)d_ws;
    const size_t mBytes   = (size_t)B_ * H_ * L_ * sizeof(float);   // 512 KB
    const size_t topBytes = (size_t)B_ * H_ * NTOP_ * sizeof(int);  // 2880 B
    const size_t plBytes  = (size_t)32 * 16 * NTOP_ * sizeof(float);
    float* M      = (float*)ws;
    int*   topIdx = (int*)(ws + mBytes);
    float* plPart = (float*)(ws + mBytes + topBytes);
    float* pOut   = (float*)(ws + mBytes + topBytes + plBytes);

    // pick split count that fits the workspace
    int nsplit = 32;
    while (nsplit > 1) {
        size_t need = mBytes + topBytes + plBytes +
                      (size_t)nsplit * 16 * NTOP_ * D_ * sizeof(float);
        if (need <= ws_size) break;
        nsplit >>= 1;
    }
    int ntiles = 32 / nsplit;

    hipMemsetAsync(d_out, 0, (size_t)out_size * sizeof(float), stream);

    compute_M_kernel<<<1024, 256, 0, stream>>>(q, k, samp, M);

    topk_kernel<<<B_ * H_, 256, 0, stream>>>(M, topIdx);

    attn_strip_kernel<<<nsplit * B_ * H_, 256, 0, stream>>>(
        q, k, v, topIdx, pOut, plPart, nsplit, ntiles);

    dim3 gn(NTOP_, B_ * H_);
    reduce_norm_kernel<<<gn, 64, 0, stream>>>(topIdx, pOut, plPart, out, nsplit);
}

// Round 6
// 162.497 us; speedup vs baseline: 2.4401x; 1.0721x over previous
//
#include <hip/hip_runtime.h>
#include <math.h>

// Problem constants (B,L,H,D) = (2,4096,8,64); sample_k = n_top = 45
#define B_ 2
#define L_ 4096
#define H_ 8
#define D_ 64
#define S_ 45
#define NTOP_ 45
#define SCALE 0.125f  // 1/sqrt(64)
#define TKEYS 128     // keys per tile

// ---------------- K1: sparsity measure M = max_s(q.k_s) - sum_s/L ----------------
// 8 lanes/query (8 queries/wave) -> 8192 waves = 32 waves/CU (grid no longer caps
// occupancy). Transposed fragment: lane l8 holds float4s {l8, 8+l8}; vmem instr j
// reads one contiguous 128B (2 lines) per query. Explicit 1-deep prefetch keeps
// >=2 gathers in flight per lane regardless of unroller behavior.
__global__ __launch_bounds__(256) void compute_M_kernel(
    const float* __restrict__ q, const float* __restrict__ k,
    const int* __restrict__ samp, float* __restrict__ M) {
    __shared__ int sIdx[32 * S_];   // 1440 ints = 5.76 KB
    int tid = threadIdx.x;
    int g   = blockIdx.x;           // 0..2047
    int xcd = g & 7;
    int s0  = g >> 3;               // 0..255
    int bh  = xcd + 8 * (s0 >> 7);  // 2 bh per XCD -> K slice stays L2-resident
    int c32 = s0 & 127;             // chunk of 32 queries
    int b = bh >> 3, h = bh & 7;
    int l0 = c32 * 32;

    const int* sbase = samp + (long)l0 * S_;
    for (int i = tid; i < 32 * S_; i += 256) sIdx[i] = sbase[i];
    __syncthreads();

    int lane = tid & 63, wave = tid >> 6;
    int l8 = lane & 7;              // cluster lane (0..7)
    int q8 = lane >> 3;             // query within wave (0..7)
    int qi = wave * 8 + q8;         // query within block (0..31)
    int l  = l0 + qi;

    const float4* qrow = (const float4*)(q + (((long)(b * L_ + l)) * H_ + h) * D_);
    float4 qa = qrow[l8], qb = qrow[8 + l8];

    const float4* kb4 = (const float4*)(k + ((long)b * L_ * H_ + h) * (long)D_);
    const int* myIdx = sIdx + qi * S_;

    int idx0 = myIdx[0];
    const float4* kr0 = kb4 + (long)idx0 * (H_ * D_ / 4);
    float4 ka = kr0[l8], kb2 = kr0[8 + l8];

    float vmax = -INFINITY, vsum = 0.f;
    #pragma unroll 5
    for (int s = 0; s < S_; ++s) {
        // prefetch next sample's row (self-prefetch on last iter, discarded)
        int sn = (s + 1 < S_) ? s + 1 : s;
        int nidx = myIdx[sn];
        const float4* nr = kb4 + (long)nidx * (H_ * D_ / 4);
        float4 na = nr[l8], nb = nr[8 + l8];

        float p = qa.x * ka.x + qa.y * ka.y + qa.z * ka.z + qa.w * ka.w
                + qb.x * kb2.x + qb.y * kb2.y + qb.z * kb2.z + qb.w * kb2.w;
        p += __shfl_xor(p, 1, 64);
        p += __shfl_xor(p, 2, 64);
        p += __shfl_xor(p, 4, 64);
        vmax = fmaxf(vmax, p);
        vsum += p;

        ka = na; kb2 = nb;
    }
    if (l8 == 0) M[(long)bh * L_ + l] = vmax - vsum * (1.0f / (float)L_);
}

// ---------------- K2: top-45 set per (b,h) via byte-radix select ----------------
// Output order is arbitrary: reference scatters context_in_q[u] to row M_top[u],
// so only the selected SET matters. Tie-break at threshold = lowest index.
__global__ __launch_bounds__(256) void topk_kernel(
    const float* __restrict__ M, int* __restrict__ topIdx) {
    __shared__ unsigned int hist[256];
    __shared__ unsigned int suf[257];
    __shared__ unsigned int wsum[4];
    __shared__ int sBin, sRemain, sCnt, sTieCnt;
    __shared__ int tie[64];

    int bh = blockIdx.x, tid = threadIdx.x;
    int lane = tid & 63, wave = tid >> 6;
    const float* row = M + (long)bh * L_;

    unsigned int key[16];
    #pragma unroll
    for (int j = 0; j < 16; ++j) {
        unsigned int bts = __float_as_uint(row[tid + 256 * j]);
        key[j] = bts ^ ((unsigned int)((int)bts >> 31) | 0x80000000u);
    }

    unsigned int prefix = 0, pmask = 0;
    int remain = NTOP_;
    #pragma unroll 1
    for (int pass = 3; pass >= 0; --pass) {
        int shift = pass * 8;
        hist[tid] = 0;
        __syncthreads();
        #pragma unroll
        for (int j = 0; j < 16; ++j) {
            if ((key[j] & pmask) == prefix)
                atomicAdd(&hist[(key[j] >> shift) & 255u], 1u);
        }
        __syncthreads();
        // suffix sum suf[t] = sum_{i>=t} hist[i]: wave scan + cross-wave combine
        unsigned int s = hist[tid];
        #pragma unroll
        for (int off = 1; off < 64; off <<= 1) {
            unsigned int o = __shfl_down(s, off, 64);
            if (lane + off < 64) s += o;
        }
        if (lane == 0) wsum[wave] = s;
        __syncthreads();
        unsigned int add = 0;
        for (int w = wave + 1; w < 4; ++w) add += wsum[w];
        s += add;
        suf[tid] = s;
        if (tid == 0) suf[256] = 0;
        __syncthreads();
        if (suf[tid] >= (unsigned int)remain && suf[tid + 1] < (unsigned int)remain) {
            sBin = tid;
            sRemain = remain - (int)suf[tid + 1];
        }
        __syncthreads();
        prefix |= ((unsigned int)sBin) << shift;
        pmask  |= 0xFFu << shift;
        remain  = sRemain;
        __syncthreads();
    }

    if (tid == 0) { sCnt = 0; sTieCnt = 0; }
    __syncthreads();
    int* outRow = topIdx + bh * NTOP_;
    #pragma unroll
    for (int j = 0; j < 16; ++j) {
        int idx = tid + 256 * j;
        if (key[j] > prefix) {
            int pos = atomicAdd(&sCnt, 1);
            outRow[pos] = idx;
        } else if (key[j] == prefix) {
            int tp = atomicAdd(&sTieCnt, 1);
            if (tp < 64) tie[tp] = idx;
        }
    }
    __syncthreads();
    if (tid == 0) {
        int base = sCnt;   // == NTOP_ - remain
        int tc = sTieCnt < 64 ? sTieCnt : 64;
        for (int t = 0; t < remain; ++t) {
            int mi = 0x7fffffff, mj = 0;
            for (int j2 = 0; j2 < tc; ++j2)
                if (tie[j2] < mi) { mi = tie[j2]; mj = j2; }
            outRow[base + t] = mi;
            tie[mj] = 0x7fffffff;
        }
    }
}

// ---------------- K3: key-strip attention, partial (Sum e*v, Sum e) per split ----------------
#define QSTRIDE 68    // padded LDS row stride for Q and K/V tiles (floats)
#define PSTRIDE 132   // padded LDS row stride for P (floats)
__global__ __launch_bounds__(256, 2) void attn_strip_kernel(
    const float* __restrict__ q, const float* __restrict__ k,
    const float* __restrict__ v, const int* __restrict__ topIdx,
    float* __restrict__ pOut, float* __restrict__ plPart,
    int nsplit, int ntiles) {
    __shared__ int   sTop[48];
    __shared__ float sQ[48 * QSTRIDE];     // 13.1 KB
    __shared__ float sKV[TKEYS * QSTRIDE]; // 34.8 KB (K, then V)
    __shared__ float sP[48 * PSTRIDE];     // 25.3 KB

    int g = blockIdx.x;
    int xcd = g & 7;
    int s0 = g >> 3;                  // 0 .. nsplit*2-1
    int grp = s0 / nsplit;            // 0..1
    int bh = xcd + 8 * grp;
    int split = s0 - grp * nsplit;
    int b = bh >> 3, h = bh & 7;
    int tid = threadIdx.x;

    if (tid < 48) sTop[tid] = (tid < NTOP_) ? topIdx[bh * NTOP_ + tid] : 0;
    __syncthreads();

    // load Q: 45 rows x 16 float4 (rows 45..47 zero)
    for (int i = tid; i < 768; i += 256) {
        int u = i >> 4, d4 = i & 15;
        float4 val = make_float4(0.f, 0.f, 0.f, 0.f);
        if (u < NTOP_) {
            int lq = sTop[u];
            val = *(const float4*)(q + (((long)(b * L_ + lq)) * H_ + h) * D_ + 4 * d4);
        }
        *(float4*)(sQ + u * QSTRIDE + 4 * d4) = val;
    }

    int tx = tid & 15, ty = tid >> 4;   // S phase: u = 3ty+i x keys tx+16j
    int dx = tid & 15, uy = tid >> 4;   // PV phase: u = 3uy+i x d = 4dx..
    float o[3][4];
    float ls[3];
    #pragma unroll
    for (int i = 0; i < 3; ++i) {
        ls[i] = 0.f;
        #pragma unroll
        for (int c = 0; c < 4; ++c) o[i][c] = 0.f;
    }

    #pragma unroll 1
    for (int tile = 0; tile < ntiles; ++tile) {
        int key0 = (split * ntiles + tile) * TKEYS;
        __syncthreads();  // prev PV (or Q-load) done before sKV overwrite
        #pragma unroll
        for (int j = 0; j < 8; ++j) {
            int i = tid + 256 * j;
            int r = i >> 4, d4 = i & 15;
            float4 val = *(const float4*)(k + (((long)(b * L_ + key0 + r)) * H_ + h) * D_ + 4 * d4);
            *(float4*)(sKV + r * QSTRIDE + 4 * d4) = val;
        }
        __syncthreads();

        float acc[3][8];
        #pragma unroll
        for (int i = 0; i < 3; ++i)
            #pragma unroll
            for (int j = 0; j < 8; ++j) acc[i][j] = 0.f;

        #pragma unroll 4
        for (int d4 = 0; d4 < 16; ++d4) {
            float4 qv[3];
            #pragma unroll
            for (int i = 0; i < 3; ++i)
                qv[i] = *(const float4*)(sQ + (3 * ty + i) * QSTRIDE + 4 * d4);
            #pragma unroll
            for (int j = 0; j < 8; ++j) {
                float4 kv = *(const float4*)(sKV + (tx + 16 * j) * QSTRIDE + 4 * d4);
                #pragma unroll
                for (int i = 0; i < 3; ++i)
                    acc[i][j] += qv[i].x * kv.x + qv[i].y * kv.y + qv[i].z * kv.z + qv[i].w * kv.w;
            }
        }
        #pragma unroll
        for (int i = 0; i < 3; ++i) {
            #pragma unroll
            for (int j = 0; j < 8; ++j)
                sP[(3 * ty + i) * PSTRIDE + tx + 16 * j] = __expf(acc[i][j] * SCALE);
        }
        __syncthreads();  // S done (K reads + P writes) before V overwrite

        #pragma unroll
        for (int j = 0; j < 8; ++j) {
            int i = tid + 256 * j;
            int r = i >> 4, d4 = i & 15;
            float4 val = *(const float4*)(v + (((long)(b * L_ + key0 + r)) * H_ + h) * D_ + 4 * d4);
            *(float4*)(sKV + r * QSTRIDE + 4 * d4) = val;
        }
        __syncthreads();

        #pragma unroll 2
        for (int k4 = 0; k4 < 32; ++k4) {
            float pa[3][4];
            #pragma unroll
            for (int i = 0; i < 3; ++i)
                *(float4*)pa[i] = *(const float4*)(sP + (3 * uy + i) * PSTRIDE + 4 * k4);
            #pragma unroll
            for (int c = 0; c < 4; ++c) {
                float4 vr = *(const float4*)(sKV + (4 * k4 + c) * QSTRIDE + 4 * dx);
                #pragma unroll
                for (int i = 0; i < 3; ++i) {
                    o[i][0] += pa[i][c] * vr.x;
                    o[i][1] += pa[i][c] * vr.y;
                    o[i][2] += pa[i][c] * vr.z;
                    o[i][3] += pa[i][c] * vr.w;
                    ls[i]   += pa[i][c];
                }
            }
        }
    }

    // store partials (contention-free)
    #pragma unroll
    for (int i = 0; i < 3; ++i) {
        int u = 3 * uy + i;
        if (u < NTOP_) {
            long base = ((long)(split * 16 + bh) * NTOP_ + u) * D_;
            *(float4*)(pOut + base + 4 * dx) = make_float4(o[i][0], o[i][1], o[i][2], o[i][3]);
            if (dx == 0) plPart[(long)(split * 16 + bh) * NTOP_ + u] = ls[i];
        }
    }
}

// ---------------- K4: reduce partials across splits, normalize, scatter to out ----------------
__global__ __launch_bounds__(64) void reduce_norm_kernel(
    const int* __restrict__ topIdx, const float* __restrict__ pOut,
    const float* __restrict__ plPart, float* __restrict__ out, int nsplit) {
    int u = blockIdx.x, bh = blockIdx.y;
    int b = bh >> 3, h = bh & 7;
    int d = threadIdx.x;
    float acc = 0.f, lsum = 0.f;
    for (int s = 0; s < nsplit; ++s) {
        acc  += pOut[((long)(s * 16 + bh) * NTOP_ + u) * D_ + d];
        lsum += plPart[(long)(s * 16 + bh) * NTOP_ + u];
    }
    int lq = topIdx[bh * NTOP_ + u];
    out[(((long)(b * L_ + lq)) * H_ + h) * D_ + d] = acc / lsum;
}

extern "C" void kernel_launch(void* const* d_in, const int* in_sizes, int n_in,
                              void* d_out, int out_size, void* d_ws, size_t ws_size,
                              hipStream_t stream) {
    const float* q = (const float*)d_in[0];
    const float* k = (const float*)d_in[1];
    const float* v = (const float*)d_in[2];
    // d_in[3] = attn_mask (unused)
    const int* samp = (const int*)d_in[4];
    float* out = (float*)d_out;

    char* ws = (char*)d_ws;
    const size_t mBytes   = (size_t)B_ * H_ * L_ * sizeof(float);   // 512 KB
    const size_t topBytes = (size_t)B_ * H_ * NTOP_ * sizeof(int);  // 2880 B
    const size_t plBytes  = (size_t)32 * 16 * NTOP_ * sizeof(float);
    float* M      = (float*)ws;
    int*   topIdx = (int*)(ws + mBytes);
    float* plPart = (float*)(ws + mBytes + topBytes);
    float* pOut   = (float*)(ws + mBytes + topBytes + plBytes);

    // pick split count that fits the workspace
    int nsplit = 32;
    while (nsplit > 1) {
        size_t need = mBytes + topBytes + plBytes +
                      (size_t)nsplit * 16 * NTOP_ * D_ * sizeof(float);
        if (need <= ws_size) break;
        nsplit >>= 1;
    }
    int ntiles = 32 / nsplit;

    hipMemsetAsync(d_out, 0, (size_t)out_size * sizeof(float), stream);

    compute_M_kernel<<<2048, 256, 0, stream>>>(q, k, samp, M);

    topk_kernel<<<B_ * H_, 256, 0, stream>>>(M, topIdx);

    attn_strip_kernel<<<nsplit * B_ * H_, 256, 0, stream>>>(
        q, k, v, topIdx, pOut, plPart, nsplit, ntiles);

    dim3 gn(NTOP_, B_ * H_);
    reduce_norm_kernel<<<gn, 64, 0, stream>>>(topIdx, pOut, plPart, out, nsplit);
}

// Round 7
// 158.921 us; speedup vs baseline: 2.4950x; 1.0225x over previous
//
#include <hip/hip_runtime.h>
#include <math.h>

// Problem constants (B,L,H,D) = (2,4096,8,64); sample_k = n_top = 45
#define B_ 2
#define L_ 4096
#define H_ 8
#define D_ 64
#define S_ 45
#define NTOP_ 45
#define SCALE 0.125f  // 1/sqrt(64)
#define TKEYS 64      // keys per attn block
#define NSPLIT 64     // key splits per (b,h)

// ---------------- K1: sparsity measure M = max_s(q.k_s) - sum_s/L ----------------
// 8 lanes/query (8 queries/wave) -> 8192 waves = 32/CU. Transposed fragment:
// lane l8 holds float4s {l8, 8+l8} (one contiguous 128B per query per instr).
// 2-deep software pipeline: 4-6 gathers in flight per lane. Index rows padded
// to stride 48 with zeros so the steady-state body has no boundary select.
__global__ __launch_bounds__(256) void compute_M_kernel(
    const float* __restrict__ q, const float* __restrict__ k,
    const int* __restrict__ samp, float* __restrict__ M) {
    __shared__ int sIdx[32 * 48];   // 6144 B
    int tid = threadIdx.x;
    int g   = blockIdx.x;           // 0..2047
    int xcd = g & 7;
    int s0  = g >> 3;               // 0..255
    int bh  = xcd + 8 * (s0 >> 7);  // 2 bh per XCD -> K slice stays L2-resident
    int c32 = s0 & 127;             // chunk of 32 queries
    int b = bh >> 3, h = bh & 7;
    int l0 = c32 * 32;

    const int* sbase = samp + (long)l0 * S_;
    for (int i = tid; i < 32 * S_; i += 256) {
        int qq = i / S_, ss = i - qq * S_;
        sIdx[qq * 48 + ss] = sbase[i];
    }
    if (tid < 96) sIdx[(tid >> 2) * 48 + S_ + (tid & 3) % 3] = 0;  // pad 45..47 = 0
    __syncthreads();

    int lane = tid & 63, wave = tid >> 6;
    int l8 = lane & 7;              // cluster lane (0..7)
    int q8 = lane >> 3;             // query within wave (0..7)
    int qi = wave * 8 + q8;         // query within block (0..31)
    int l  = l0 + qi;

    const float4* qrow = (const float4*)(q + (((long)(b * L_ + l)) * H_ + h) * D_);
    float4 qa = qrow[l8], qb = qrow[8 + l8];

    const float4* kb4 = (const float4*)(k + ((long)b * L_ * H_ + h) * (long)D_);
    const int* myIdx = sIdx + qi * 48;

    const float4* r0 = kb4 + (long)myIdx[0] * (H_ * D_ / 4);
    float4 ka0 = r0[l8], kb0 = r0[8 + l8];
    const float4* r1 = kb4 + (long)myIdx[1] * (H_ * D_ / 4);
    float4 ka1 = r1[l8], kb1 = r1[8 + l8];

    float vmax = -INFINITY, vsum = 0.f;
    #pragma unroll 3
    for (int s = 0; s < S_; ++s) {
        int nidx = myIdx[s + 2];    // padded: safe reads of row 0 at tail
        const float4* nr = kb4 + (long)nidx * (H_ * D_ / 4);
        float4 na = nr[l8], nb = nr[8 + l8];

        float p = qa.x * ka0.x + qa.y * ka0.y + qa.z * ka0.z + qa.w * ka0.w
                + qb.x * kb0.x + qb.y * kb0.y + qb.z * kb0.z + qb.w * kb0.w;
        p += __shfl_xor(p, 1, 64);
        p += __shfl_xor(p, 2, 64);
        p += __shfl_xor(p, 4, 64);
        vmax = fmaxf(vmax, p);
        vsum += p;

        ka0 = ka1; kb0 = kb1;
        ka1 = na;  kb1 = nb;
    }
    if (l8 == 0) M[(long)bh * L_ + l] = vmax - vsum * (1.0f / (float)L_);
}

// ---------------- K2: top-45 set per (b,h) via byte-radix select ----------------
// Output order is arbitrary: reference scatters context_in_q[u] to row M_top[u],
// so only the selected SET matters. Tie-break at threshold = lowest index.
__global__ __launch_bounds__(256) void topk_kernel(
    const float* __restrict__ M, int* __restrict__ topIdx) {
    __shared__ unsigned int hist[256];
    __shared__ unsigned int suf[257];
    __shared__ unsigned int wsum[4];
    __shared__ int sBin, sRemain, sCnt, sTieCnt;
    __shared__ int tie[64];

    int bh = blockIdx.x, tid = threadIdx.x;
    int lane = tid & 63, wave = tid >> 6;
    const float* row = M + (long)bh * L_;

    unsigned int key[16];
    #pragma unroll
    for (int j = 0; j < 16; ++j) {
        unsigned int bts = __float_as_uint(row[tid + 256 * j]);
        key[j] = bts ^ ((unsigned int)((int)bts >> 31) | 0x80000000u);
    }

    unsigned int prefix = 0, pmask = 0;
    int remain = NTOP_;
    #pragma unroll 1
    for (int pass = 3; pass >= 0; --pass) {
        int shift = pass * 8;
        hist[tid] = 0;
        __syncthreads();
        #pragma unroll
        for (int j = 0; j < 16; ++j) {
            if ((key[j] & pmask) == prefix)
                atomicAdd(&hist[(key[j] >> shift) & 255u], 1u);
        }
        __syncthreads();
        // suffix sum suf[t] = sum_{i>=t} hist[i]
        unsigned int s = hist[tid];
        #pragma unroll
        for (int off = 1; off < 64; off <<= 1) {
            unsigned int o = __shfl_down(s, off, 64);
            if (lane + off < 64) s += o;
        }
        if (lane == 0) wsum[wave] = s;
        __syncthreads();
        unsigned int add = 0;
        for (int w = wave + 1; w < 4; ++w) add += wsum[w];
        s += add;
        suf[tid] = s;
        if (tid == 0) suf[256] = 0;
        __syncthreads();
        if (suf[tid] >= (unsigned int)remain && suf[tid + 1] < (unsigned int)remain) {
            sBin = tid;
            sRemain = remain - (int)suf[tid + 1];
        }
        __syncthreads();
        prefix |= ((unsigned int)sBin) << shift;
        pmask  |= 0xFFu << shift;
        remain  = sRemain;
        __syncthreads();
    }

    if (tid == 0) { sCnt = 0; sTieCnt = 0; }
    __syncthreads();
    int* outRow = topIdx + bh * NTOP_;
    #pragma unroll
    for (int j = 0; j < 16; ++j) {
        int idx = tid + 256 * j;
        if (key[j] > prefix) {
            int pos = atomicAdd(&sCnt, 1);
            outRow[pos] = idx;
        } else if (key[j] == prefix) {
            int tp = atomicAdd(&sTieCnt, 1);
            if (tp < 64) tie[tp] = idx;
        }
    }
    __syncthreads();
    if (tid == 0) {
        int base = sCnt;   // == NTOP_ - remain
        int tc = sTieCnt < 64 ? sTieCnt : 64;
        for (int t = 0; t < remain; ++t) {
            int mi = 0x7fffffff, mj = 0;
            for (int j2 = 0; j2 < tc; ++j2)
                if (tie[j2] < mi) { mi = tie[j2]; mj = j2; }
            outRow[base + t] = mi;
            tie[mj] = 0x7fffffff;
        }
    }
}

// ---------------- K3: key-strip attention, all-up-front loads, 2 barriers ----------------
// grid = NSPLIT*16 blocks. Q, K, V loaded into separate LDS buffers in one issue
// burst (one vmcnt drain, one barrier), then S -> barrier -> PV.
#define STRIDE 68     // padded LDS row stride (floats)
__global__ __launch_bounds__(256, 2) void attn_strip_kernel(
    const float* __restrict__ q, const float* __restrict__ k,
    const float* __restrict__ v, const int* __restrict__ topIdx,
    float* __restrict__ pOut, float* __restrict__ plPart, int nsplit) {
    __shared__ float sQ[48 * STRIDE];     // 13.1 KB
    __shared__ float sK[TKEYS * STRIDE];  // 17.4 KB
    __shared__ float sV[TKEYS * STRIDE];  // 17.4 KB
    __shared__ float sP[48 * STRIDE];     // 13.1 KB  (64 keys + pad)

    int g = blockIdx.x;
    int xcd = g & 7;
    int s0 = g >> 3;                  // 0 .. nsplit*2-1
    int grp = s0 / nsplit;            // 0..1
    int bh = xcd + 8 * grp;
    int split = s0 - grp * nsplit;
    int b = bh >> 3, h = bh & 7;
    int tid = threadIdx.x;
    int key0 = split * TKEYS;

    // ---- issue ALL global loads up front ----
    // Q: 48 rows x 16 float4 = 768 -> 3/thread (topIdx read direct, L2-hot)
    #pragma unroll
    for (int j = 0; j < 3; ++j) {
        int i = tid + 256 * j;
        int u = i >> 4, d4 = i & 15;
        float4 val = make_float4(0.f, 0.f, 0.f, 0.f);
        if (u < NTOP_) {
            int lq = topIdx[bh * NTOP_ + u];
            val = *(const float4*)(q + (((long)(b * L_ + lq)) * H_ + h) * D_ + 4 * d4);
        }
        *(float4*)(sQ + u * STRIDE + 4 * d4) = val;
    }
    // K and V: 64 rows x 16 float4 = 1024 each -> 4/thread each
    #pragma unroll
    for (int j = 0; j < 4; ++j) {
        int i = tid + 256 * j;
        int r = i >> 4, d4 = i & 15;
        long off = (((long)(b * L_ + key0 + r)) * H_ + h) * D_ + 4 * d4;
        *(float4*)(sK + r * STRIDE + 4 * d4) = *(const float4*)(k + off);
        *(float4*)(sV + r * STRIDE + 4 * d4) = *(const float4*)(v + off);
    }
    __syncthreads();

    // ---- S phase: thread (ty,tx): u = 3ty+i (i<3) x keys tx+16j (j<4) ----
    int tx = tid & 15, ty = tid >> 4;
    float acc[3][4];
    #pragma unroll
    for (int i = 0; i < 3; ++i)
        #pragma unroll
        for (int j = 0; j < 4; ++j) acc[i][j] = 0.f;

    #pragma unroll 4
    for (int d4 = 0; d4 < 16; ++d4) {
        float4 qv[3];
        #pragma unroll
        for (int i = 0; i < 3; ++i)
            qv[i] = *(const float4*)(sQ + (3 * ty + i) * STRIDE + 4 * d4);
        #pragma unroll
        for (int j = 0; j < 4; ++j) {
            float4 kv = *(const float4*)(sK + (tx + 16 * j) * STRIDE + 4 * d4);
            #pragma unroll
            for (int i = 0; i < 3; ++i)
                acc[i][j] += qv[i].x * kv.x + qv[i].y * kv.y + qv[i].z * kv.z + qv[i].w * kv.w;
        }
    }
    #pragma unroll
    for (int i = 0; i < 3; ++i) {
        #pragma unroll
        for (int j = 0; j < 4; ++j)
            sP[(3 * ty + i) * STRIDE + tx + 16 * j] = __expf(acc[i][j] * SCALE);
    }
    __syncthreads();

    // ---- PV phase: thread (uy,dx): u = 3uy+i (i<3) x d = 4dx..4dx+3 ----
    int dx = tid & 15, uy = tid >> 4;
    float o[3][4];
    float ls[3];
    #pragma unroll
    for (int i = 0; i < 3; ++i) {
        ls[i] = 0.f;
        #pragma unroll
        for (int c = 0; c < 4; ++c) o[i][c] = 0.f;
    }
    #pragma unroll 4
    for (int k4 = 0; k4 < 16; ++k4) {
        float pa[3][4];
        #pragma unroll
        for (int i = 0; i < 3; ++i)
            *(float4*)pa[i] = *(const float4*)(sP + (3 * uy + i) * STRIDE + 4 * k4);
        #pragma unroll
        for (int c = 0; c < 4; ++c) {
            float4 vr = *(const float4*)(sV + (4 * k4 + c) * STRIDE + 4 * dx);
            #pragma unroll
            for (int i = 0; i < 3; ++i) {
                o[i][0] += pa[i][c] * vr.x;
                o[i][1] += pa[i][c] * vr.y;
                o[i][2] += pa[i][c] * vr.z;
                o[i][3] += pa[i][c] * vr.w;
                ls[i]   += pa[i][c];
            }
        }
    }
    // store partials (contention-free)
    #pragma unroll
    for (int i = 0; i < 3; ++i) {
        int u = 3 * uy + i;
        if (u < NTOP_) {
            long base = ((long)(split * 16 + bh) * NTOP_ + u) * D_;
            *(float4*)(pOut + base + 4 * dx) = make_float4(o[i][0], o[i][1], o[i][2], o[i][3]);
            if (dx == 0) plPart[(long)(split * 16 + bh) * NTOP_ + u] = ls[i];
        }
    }
}

// ---------------- K4: reduce partials across splits, normalize, scatter ----------------
__global__ __launch_bounds__(256) void reduce_norm_kernel(
    const int* __restrict__ topIdx, const float* __restrict__ pOut,
    const float* __restrict__ plPart, float* __restrict__ out, int nsplit) {
    __shared__ float part[4][64];
    __shared__ float lpart[4];
    int u = blockIdx.x, bh = blockIdx.y;
    int b = bh >> 3, h = bh & 7;
    int tid = threadIdx.x;
    int d = tid & 63, sg = tid >> 6;
    float acc = 0.f, lsum = 0.f;
    for (int s = sg; s < nsplit; s += 4) {
        acc  += pOut[((long)(s * 16 + bh) * NTOP_ + u) * D_ + d];
        lsum += plPart[(long)(s * 16 + bh) * NTOP_ + u];
    }
    part[sg][d] = acc;
    if (d == 0) lpart[sg] = lsum;
    __syncthreads();
    if (sg == 0) {
        float a = part[0][d] + part[1][d] + part[2][d] + part[3][d];
        float lt = lpart[0] + lpart[1] + lpart[2] + lpart[3];
        int lq = topIdx[bh * NTOP_ + u];
        out[(((long)(b * L_ + lq)) * H_ + h) * D_ + d] = a / lt;
    }
}

extern "C" void kernel_launch(void* const* d_in, const int* in_sizes, int n_in,
                              void* d_out, int out_size, void* d_ws, size_t ws_size,
                              hipStream_t stream) {
    const float* q = (const float*)d_in[0];
    const float* k = (const float*)d_in[1];
    const float* v = (const float*)d_in[2];
    // d_in[3] = attn_mask (unused)
    const int* samp = (const int*)d_in[4];
    float* out = (float*)d_out;

    char* ws = (char*)d_ws;
    const size_t mBytes   = (size_t)B_ * H_ * L_ * sizeof(float);   // 512 KB
    const size_t topBytes = (size_t)B_ * H_ * NTOP_ * sizeof(int);  // 2880 B
    const size_t plBytes  = (size_t)NSPLIT * 16 * NTOP_ * sizeof(float);
    float* M      = (float*)ws;
    int*   topIdx = (int*)(ws + mBytes);
    float* plPart = (float*)(ws + mBytes + topBytes);
    float* pOut   = (float*)(ws + mBytes + topBytes + plBytes);

    // pick split count that fits the workspace
    int nsplit = NSPLIT;
    while (nsplit > 1) {
        size_t need = mBytes + topBytes + plBytes +
                      (size_t)nsplit * 16 * NTOP_ * D_ * sizeof(float);
        if (need <= ws_size) break;
        nsplit >>= 1;
    }

    hipMemsetAsync(d_out, 0, (size_t)out_size * sizeof(float), stream);

    compute_M_kernel<<<2048, 256, 0, stream>>>(q, k, samp, M);

    topk_kernel<<<B_ * H_, 256, 0, stream>>>(M, topIdx);

    attn_strip_kernel<<<nsplit * B_ * H_, 256, 0, stream>>>(
        q, k, v, topIdx, pOut, plPart, nsplit);

    dim3 gn(NTOP_, B_ * H_);
    reduce_norm_kernel<<<gn, 256, 0, stream>>>(topIdx, pOut, plPart, out, nsplit);
}